// Round 1
// baseline (154.152 us; speedup 1.0000x reference)
//
#include <hip/hip_runtime.h>

#define N_NODES 100000
#define D 128
#define E_POS 262144
#define E_NEG 262144
#define E_TOT (E_POS + E_NEG)
#define NT 1563           // ceil(N_NODES/64) node tiles

typedef __attribute__((ext_vector_type(8))) short short8;  // 8 bf16 (4 VGPRs)
typedef __attribute__((ext_vector_type(4))) float f4;      // MFMA C/D frag

__device__ __forceinline__ unsigned f2bf_u(float f) {
    // round-to-nearest-even fp32 -> bf16 (inputs finite; no NaN path)
    unsigned u = __float_as_uint(f);
    return (u + 0x7fffu + ((u >> 16) & 1u)) >> 16;
}

// ---------------------------------------------------------------------------
// Phase 1 (bf16 MFMA, swapped orientation, persistent + pipelined):
//   UVb[n][j<128] = sum_k x[n][k]*W1[k][j] + b1[j]      (U)
//   UVb[n][128+j] = sum_k x[n][k]*W1[128+k][j]          (V)
// 512 thr = 8 waves; 64 nodes x 256 cols per tile; wave w -> h=w>>2 half,
// 32-col slice (w&3)*32. D[m=j][n=node] = Wf(A) * x(B): per lane the C frag
// is 4 CONSECUTIVE j for one node -> epilogue ds_write_b64.
// Persistent: each block loops tiles bid, bid+grid; x loads for the NEXT
// tile issue right after bar1, overlapping this tile's MFMA + epilogue.
//
// W1 pack FUSED (this round): instead of a separate pack_w1 kernel + global
// Wf buffer, each thread builds its 8 A-operand frags directly from fp32 W1:
//   wfr[ks][ct][j] = bf16( W1[(h*128 + ks*32 + q*8 + j)*128
//                             + cbase + ct*16 + m16] )
// 16 lanes (m16) read consecutive columns -> 64-B coalesced segments; W1 is
// 128 KB so blocks after the first read it from L2/L3 (~3 us hidden under
// the prologue x loads). Removes one dispatch + the Wf round-trip.
//
// All 8 Wf frags held in VGPRs for the whole kernel (tile-invariant).
// __launch_bounds__(512,4): 128-VGPR budget -> ILP; LDS 51.2KB -> 3 blk/CU.
// Two barriers/tile: stage-write->compute-read and epi-write->epi-read
// (separate LDS regions make the third barrier redundant; see comments).
// MFMA layouts (measured, m89/m91): A[m=lane&15][k=q*8+j],
// B[k=q*8+j][n=lane&15], C: col(n)=lane&15, row(m)=q*4+reg.
// ---------------------------------------------------------------------------
#define XRS 136   // staging row stride in shorts (272 B: 16-B aligned)
#define ERS 264   // epilogue row stride in shorts (528 B: 16-B aligned)
#define GRID1 783 // gemm grid: ~3 blocks/CU-generation, 2 tiles/block max

__global__ __launch_bounds__(512, 4) void node_gemm_mfma(
    const float* __restrict__ x,            // [N, 128]
    const float* __restrict__ W1,           // [256, 128] fp32
    const float* __restrict__ b1,           // [128]
    unsigned short* __restrict__ UVb)       // [N, 256] bf16
{
    __shared__ unsigned short Ls[64 * XRS + 64 * ERS];  // 51200 B
    unsigned short* const Es = Ls + 64 * XRS;           // epilogue region

    const int t    = threadIdx.x;
    const int w    = t >> 6;                // wave 0..7
    const int lane = t & 63;
    const int m16  = lane & 15;
    const int q    = lane >> 4;             // quad 0..3
    const int h    = w >> 2;                // 0=U, 1=V
    const int cbase = (w & 3) * 32;         // col slice within half

    // ---- prologue: issue x loads for first tile FIRST (HBM, long latency) --
    int tile = blockIdx.x;
    float4 xr[4];
#pragma unroll
    for (int i = 0; i < 4; ++i) {
        const int s  = t + i * 512;
        int gr = tile * 64 + (s >> 5);
        if (gr >= N_NODES) gr = N_NODES - 1;
        xr[i] = *(const float4*)(x + (size_t)gr * D + (s & 31) * 4);
    }

    // ---- tile-invariant: build Wf frags in-register from fp32 W1 ----
    // (8 x short8 = 32 VGPRs; loads are 64-B coalesced per 16-lane group,
    //  L2-hit for all but the first blocks)
    short8 wfr[4][2];
#pragma unroll
    for (int ks = 0; ks < 4; ++ks) {
        const int kb = h * 128 + ks * 32 + q * 8;
#pragma unroll
        for (int ct = 0; ct < 2; ++ct) {
            const float* src = W1 + (size_t)kb * D + cbase + ct * 16 + m16;
            float f[8];
#pragma unroll
            for (int j = 0; j < 8; ++j) f[j] = src[(size_t)j * D];
            short8 wv;
#pragma unroll
            for (int j = 0; j < 8; ++j) wv[j] = (short)f2bf_u(f[j]);
            wfr[ks][ct] = wv;
        }
    }
    float4 badd[2];
#pragma unroll
    for (int ct = 0; ct < 2; ++ct)
        badd[ct] = (h == 0) ? *(const float4*)(b1 + cbase + ct * 16 + q * 4)
                            : make_float4(0.f, 0.f, 0.f, 0.f);

    for (; tile < NT; tile += GRID1) {
        const int nb = tile * 64;

        // ---- stage x regs -> bf16 LDS ----
#pragma unroll
        for (int i = 0; i < 4; ++i) {
            const int s = t + i * 512;
            const unsigned p0 = (f2bf_u(xr[i].y) << 16) | f2bf_u(xr[i].x);
            const unsigned p1 = (f2bf_u(xr[i].w) << 16) | f2bf_u(xr[i].z);
            *(uint2*)&Ls[(s >> 5) * XRS + (s & 31) * 4] = make_uint2(p0, p1);
        }
        __syncthreads();   // bar1: stage visible; also guards prev epi reads

        // ---- prefetch next tile's x while computing this one ----
        const int ntile = tile + GRID1;
        float4 xr2[4];
        if (ntile < NT) {
#pragma unroll
            for (int i = 0; i < 4; ++i) {
                const int s  = t + i * 512;
                int gr = ntile * 64 + (s >> 5);
                if (gr >= N_NODES) gr = N_NODES - 1;
                xr2[i] = *(const float4*)(x + (size_t)gr * D + (s & 31) * 4);
            }
        } else {
#pragma unroll
            for (int i = 0; i < 4; ++i) xr2[i] = xr[i];
        }

        // ---- MFMA: A=Wf(W1^T), B=x -> D[m=j][n=node] ----
        f4 acc[4][2];
#pragma unroll
        for (int i = 0; i < 4; ++i)
#pragma unroll
            for (int j = 0; j < 2; ++j) acc[i][j] = (f4){0.f, 0.f, 0.f, 0.f};

#pragma unroll
        for (int ks = 0; ks < 4; ++ks) {
            const int kcol = ks * 32 + q * 8;
            short8 xf[4];
#pragma unroll
            for (int rt = 0; rt < 4; ++rt)
                xf[rt] = *(const short8*)&Ls[(rt * 16 + m16) * XRS + kcol];
#pragma unroll
            for (int rt = 0; rt < 4; ++rt)
#pragma unroll
                for (int ct = 0; ct < 2; ++ct)
                    acc[rt][ct] = __builtin_amdgcn_mfma_f32_16x16x32_bf16(
                        wfr[ks][ct], xf[rt], acc[rt][ct], 0, 0, 0);
        }

        // ---- epilogue: C-frags -> Es row-major (b64 per frag) ----
        // (no barrier needed before this: Es != stage region; prev-iter Es
        //  reads completed before this iter's bar1)
#pragma unroll
        for (int rt = 0; rt < 4; ++rt)
#pragma unroll
            for (int ct = 0; ct < 2; ++ct) {
                const int node = rt * 16 + m16;
                const int j    = h * 128 + cbase + ct * 16 + q * 4;
                const unsigned p0 =
                    (f2bf_u(acc[rt][ct][1] + badd[ct].y) << 16) |
                     f2bf_u(acc[rt][ct][0] + badd[ct].x);
                const unsigned p1 =
                    (f2bf_u(acc[rt][ct][3] + badd[ct].w) << 16) |
                     f2bf_u(acc[rt][ct][2] + badd[ct].z);
                *(uint2*)&Es[node * ERS + j] = make_uint2(p0, p1);
            }
        __syncthreads();   // bar2: epi visible (also: all stage reads done,
                           // so next iter may rewrite stage after loop)

        // ---- coalesced store: row t>>3, 32-col chunk (t&7)*32 (64 B) ----
        const int r    = t >> 3;
        const int c0   = (t & 7) * 32;
        const int grow = nb + r;
        if (grow < N_NODES) {
            const uint4* s = (const uint4*)&Es[r * ERS + c0];
            uint4* d = (uint4*)(UVb + (size_t)grow * 256 + c0);
#pragma unroll
            for (int i = 0; i < 4; ++i) d[i] = s[i];
        }

#pragma unroll
        for (int i = 0; i < 4; ++i) xr[i] = xr2[i];
    }
}

// ---------------------------------------------------------------------------
// Phase 2 (measured at gather roofline ~6.7 TB/s effective — unchanged):
// out[e] = relu(U[src]+V[tar]) . W2 + b2, UV in bf16.
// Block = 256 thr, 512 edges. Indices staged coalesced into LDS once.
// Each 16-lane group: 4 edges/iter, 8 independent 16-B gathers, 8 iters,
// unroll 2 -> up to 16 gathers in flight. float4 output stores.
// ---------------------------------------------------------------------------
__global__ __launch_bounds__(256) void edge_score_bf(
    const unsigned short* __restrict__ UVb,
    const int* __restrict__ pos,            // [2, E_POS]
    const int* __restrict__ neg,            // [2, E_NEG]
    const float* __restrict__ W2,           // [128]
    const float* __restrict__ b2,           // [1]
    float* __restrict__ out)                // [E_TOT]
{
    __shared__ int sidx[512], tidx[512];

    const int t   = threadIdx.x;
    const int bid = blockIdx.x;
    const int e0  = bid * 512;                       // global edge base
    const int* eidx = (bid < 512) ? pos : neg;       // E_POS = 512*512
    const int lb    = (bid < 512) ? e0 : e0 - E_POS;

    {
        const int2 sp = *(const int2*)(eidx + lb + 2 * t);
        const int2 tp = *(const int2*)(eidx + E_POS + lb + 2 * t);
        *(int2*)&sidx[2 * t] = sp;
        *(int2*)&tidx[2 * t] = tp;
    }
    __syncthreads();

    const int g   = t >> 4;
    const int l16 = t & 15;
    const float4 wa = *(const float4*)(W2 + l16 * 8);
    const float4 wb = *(const float4*)(W2 + l16 * 8 + 4);
    const float bb = b2[0];

#define BF_LO(uv) __uint_as_float((uv) << 16)
#define BF_HI(uv) __uint_as_float((uv) & 0xffff0000u)
#define ACC8(P, U, V)                                                   \
    P = fmaf(fmaxf(BF_LO(U.x) + BF_LO(V.x), 0.f), wa.x, P);             \
    P = fmaf(fmaxf(BF_HI(U.x) + BF_HI(V.x), 0.f), wa.y, P);             \
    P = fmaf(fmaxf(BF_LO(U.y) + BF_LO(V.y), 0.f), wa.z, P);             \
    P = fmaf(fmaxf(BF_HI(U.y) + BF_HI(V.y), 0.f), wa.w, P);             \
    P = fmaf(fmaxf(BF_LO(U.z) + BF_LO(V.z), 0.f), wb.x, P);             \
    P = fmaf(fmaxf(BF_HI(U.z) + BF_HI(V.z), 0.f), wb.y, P);             \
    P = fmaf(fmaxf(BF_LO(U.w) + BF_LO(V.w), 0.f), wb.z, P);             \
    P = fmaf(fmaxf(BF_HI(U.w) + BF_HI(V.w), 0.f), wb.w, P);

#pragma unroll 2
    for (int k = 0; k < 8; ++k) {
        const int el = k * 64 + g * 4;      // 4 consecutive local edges
        const int4 ss = *(const int4*)&sidx[el];
        const int4 tt = *(const int4*)&tidx[el];
        const uint4 U0 = *(const uint4*)(UVb + (size_t)ss.x * 256 + l16 * 8);
        const uint4 U1 = *(const uint4*)(UVb + (size_t)ss.y * 256 + l16 * 8);
        const uint4 U2 = *(const uint4*)(UVb + (size_t)ss.z * 256 + l16 * 8);
        const uint4 U3 = *(const uint4*)(UVb + (size_t)ss.w * 256 + l16 * 8);
        const uint4 V0 = *(const uint4*)(UVb + (size_t)tt.x * 256 + 128 + l16 * 8);
        const uint4 V1 = *(const uint4*)(UVb + (size_t)tt.y * 256 + 128 + l16 * 8);
        const uint4 V2 = *(const uint4*)(UVb + (size_t)tt.z * 256 + 128 + l16 * 8);
        const uint4 V3 = *(const uint4*)(UVb + (size_t)tt.w * 256 + 128 + l16 * 8);

        float p0 = 0.f, p1 = 0.f, p2 = 0.f, p3 = 0.f;
        ACC8(p0, U0, V0)
        ACC8(p1, U1, V1)
        ACC8(p2, U2, V2)
        ACC8(p3, U3, V3)

#pragma unroll
        for (int off = 8; off; off >>= 1) {
            p0 += __shfl_xor(p0, off, 64);
            p1 += __shfl_xor(p1, off, 64);
            p2 += __shfl_xor(p2, off, 64);
            p3 += __shfl_xor(p3, off, 64);
        }

        if (l16 == 0)
            *(float4*)(out + e0 + el) =
                make_float4(p0 + bb, p1 + bb, p2 + bb, p3 + bb);
    }
#undef ACC8
#undef BF_LO
#undef BF_HI
}

// ---------------------------------------------------------------------------
// Fallback (ws too small): one wave per edge, direct fp32 compute.
// ---------------------------------------------------------------------------
__global__ __launch_bounds__(64) void edge_naive(
    const float* __restrict__ x,
    const int* __restrict__ pos, const int* __restrict__ neg,
    const float* __restrict__ W1, const float* __restrict__ b1,
    const float* __restrict__ W2, const float* __restrict__ b2,
    float* __restrict__ out)
{
    const int lane = threadIdx.x;
    for (int e = blockIdx.x; e < E_TOT; e += gridDim.x) {
        int src, tar;
        if (e < E_POS) { src = pos[e]; tar = pos[E_POS + e]; }
        else { int e2 = e - E_POS; src = neg[e2]; tar = neg[E_NEG + e2]; }
        const float* xsrc = x + (size_t)src * D;
        const float* xtar = x + (size_t)tar * D;
        int j = lane * 2;
        float h0 = b1[j], h1 = b1[j + 1];
        for (int k = 0; k < D; ++k) {
            float a = xsrc[k], b = xtar[k];
            h0 = fmaf(a, W1[(size_t)k * D + j],       h0);
            h0 = fmaf(b, W1[(size_t)(k + D) * D + j], h0);
            h1 = fmaf(a, W1[(size_t)k * D + j + 1],       h1);
            h1 = fmaf(b, W1[(size_t)(k + D) * D + j + 1], h1);
        }
        float p = fmaf(fmaxf(h0, 0.f), W2[j], fmaxf(h1, 0.f) * W2[j + 1]);
#pragma unroll
        for (int off = 32; off > 0; off >>= 1) p += __shfl_xor(p, off, 64);
        if (lane == 0) out[e] = p + b2[0];
    }
}

extern "C" void kernel_launch(void* const* d_in, const int* in_sizes, int n_in,
                              void* d_out, int out_size, void* d_ws, size_t ws_size,
                              hipStream_t stream) {
    const float* x   = (const float*)d_in[0];
    const int*   pos = (const int*)d_in[1];
    const int*   neg = (const int*)d_in[2];
    const float* W1  = (const float*)d_in[3];
    const float* b1  = (const float*)d_in[4];
    const float* W2  = (const float*)d_in[5];
    const float* b2  = (const float*)d_in[6];
    float* out = (float*)d_out;

    const size_t uv_bytes = (size_t)N_NODES * 256 * sizeof(unsigned short);
    if (ws_size >= uv_bytes) {
        unsigned short* UVb = (unsigned short*)d_ws;
        node_gemm_mfma<<<GRID1, 512, 0, stream>>>(x, W1, b1, UVb);
        edge_score_bf<<<E_TOT / 512, 256, 0, stream>>>(UVb, pos, neg, W2, b2, out);
    } else {
        edge_naive<<<8192, 64, 0, stream>>>(x, pos, neg, W1, b1, W2, b2, out);
    }
}

// Round 2
// 150.105 us; speedup vs baseline: 1.0270x; 1.0270x over previous
//
#include <hip/hip_runtime.h>

#define N_NODES 100000
#define D 128
#define E_POS 262144
#define E_NEG 262144
#define E_TOT (E_POS + E_NEG)
#define NT 1563           // ceil(N_NODES/64) node tiles

typedef __attribute__((ext_vector_type(8))) short short8;  // 8 bf16 (4 VGPRs)
typedef __attribute__((ext_vector_type(4))) float f4;      // MFMA C/D frag

__device__ __forceinline__ unsigned f2bf_u(float f) {
    // round-to-nearest-even fp32 -> bf16 (inputs finite; no NaN path)
    unsigned u = __float_as_uint(f);
    return (u + 0x7fffu + ((u >> 16) & 1u)) >> 16;
}

// ---------------------------------------------------------------------------
// Prep: pack W1 (fp32 [256,128]) into bf16 MFMA fragment layout:
//   Wf[((h*4+ks)*4+q)*128 + c][j] = bf16( W1[h*128 + ks*32 + q*8 + j][c] )
// Serves as the A-operand (W1^T) in the swapped-orientation MFMA.
// 64 KB total (L2-resident). Separate dispatch measured FASTER than fusing
// the pack into the GEMM (R0: fused = +3.4 us — fp32 W1 re-read per block
// doubles L2 traffic and adds pre-loop VGPR pressure at the 128-reg budget).
// ---------------------------------------------------------------------------
__global__ __launch_bounds__(256) void pack_w1(
    const float* __restrict__ W1, unsigned short* __restrict__ Wf)
{
    const int tid = blockIdx.x * 256 + threadIdx.x;   // 4096 groups
    if (tid >= 4096) return;
    const int h  = tid >> 11;
    const int ks = (tid >> 9) & 3;
    const int q  = (tid >> 7) & 3;
    const int c  = tid & 127;
    const int kb = h * 128 + ks * 32 + q * 8;
    const float* src = W1 + (size_t)kb * D + c;
    unsigned short tmp[8];
#pragma unroll
    for (int j = 0; j < 8; ++j) tmp[j] = (unsigned short)f2bf_u(src[(size_t)j * D]);
    *(uint4*)(Wf + (size_t)tid * 8) = *(const uint4*)tmp;
}

// ---------------------------------------------------------------------------
// Phase 1 (bf16 MFMA, swapped orientation, persistent + pipelined):
//   UVb[n][j<128] = sum_k x[n][k]*W1[k][j] + b1[j]      (U)
//   UVb[n][128+j] = sum_k x[n][k]*W1[128+k][j]          (V)
// 512 thr = 8 waves; 64 nodes x 256 cols per tile; wave w -> h=w>>2 half,
// 32-col slice (w&3)*32. D[m=j][n=node] = Wf(A) * x(B): per lane the C frag
// is 4 CONSECUTIVE j for one node -> epilogue ds_write_b64.
// Persistent: each block loops tiles bid, bid+grid; x loads for the NEXT
// tile issue right after bar1, overlapping this tile's MFMA + epilogue.
// All 8 Wf frags held in VGPRs for the whole kernel (L2-hot, tile-invariant).
// __launch_bounds__(512,4): 128-VGPR budget -> ILP; LDS 51.2KB.
//
// GRID1 = 512 (this round): resident capacity is VGPR-bound at 2 blocks/CU
// (8 waves @ ~128 VGPR -> 4 waves/SIMD -> 2 blocks/CU; the LDS bound of 3
// never binds), i.e. 512 co-resident blocks. 783 blocks dispatched in TWO
// rounds with a half-empty tail; 512 dispatches in ONE round, 3 tiles/block
// (startup Wf+x latency amortized over 3 tiles, prefetch covers 2 of 3),
// and Wf re-read traffic drops 783->512 blocks.
//
// Two barriers/tile: stage-write->compute-read and epi-write->epi-read
// (separate LDS regions make the third barrier redundant; see comments).
// MFMA layouts (measured, m89/m91): A[m=lane&15][k=q*8+j],
// B[k=q*8+j][n=lane&15], C: col(n)=lane&15, row(m)=q*4+reg.
// ---------------------------------------------------------------------------
#define XRS 136   // staging row stride in shorts (272 B: 16-B aligned)
#define ERS 264   // epilogue row stride in shorts (528 B: 16-B aligned)
#define GRID1 512 // gemm grid: exactly one co-resident round (2 blk/CU)

__global__ __launch_bounds__(512, 4) void node_gemm_mfma(
    const float* __restrict__ x,            // [N, 128]
    const unsigned short* __restrict__ Wf,  // packed W1^T frags
    const float* __restrict__ b1,           // [128]
    unsigned short* __restrict__ UVb)       // [N, 256] bf16
{
    __shared__ unsigned short Ls[64 * XRS + 64 * ERS];  // 51200 B
    unsigned short* const Es = Ls + 64 * XRS;           // epilogue region

    const int t    = threadIdx.x;
    const int w    = t >> 6;                // wave 0..7
    const int lane = t & 63;
    const int m16  = lane & 15;
    const int q    = lane >> 4;             // quad 0..3
    const int h    = w >> 2;                // 0=U, 1=V
    const int cbase = (w & 3) * 32;         // col slice within half

    // ---- tile-invariant: Wf frags (8 x short8 = 32 VGPRs) + b1 ----
    short8 wfr[4][2];
#pragma unroll
    for (int ks = 0; ks < 4; ++ks) {
        const unsigned short* wfb =
            Wf + ((size_t)(((h * 4 + ks) * 4 + q) * 128 + cbase + m16)) * 8;
        wfr[ks][0] = *(const short8*)wfb;
        wfr[ks][1] = *(const short8*)(wfb + 16 * 8);
    }
    float4 badd[2];
#pragma unroll
    for (int ct = 0; ct < 2; ++ct)
        badd[ct] = (h == 0) ? *(const float4*)(b1 + cbase + ct * 16 + q * 4)
                            : make_float4(0.f, 0.f, 0.f, 0.f);

    // ---- prologue: issue x loads for first tile ----
    int tile = blockIdx.x;
    float4 xr[4];
#pragma unroll
    for (int i = 0; i < 4; ++i) {
        const int s  = t + i * 512;
        int gr = tile * 64 + (s >> 5);
        if (gr >= N_NODES) gr = N_NODES - 1;
        xr[i] = *(const float4*)(x + (size_t)gr * D + (s & 31) * 4);
    }

    for (; tile < NT; tile += GRID1) {
        const int nb = tile * 64;

        // ---- stage x regs -> bf16 LDS ----
#pragma unroll
        for (int i = 0; i < 4; ++i) {
            const int s = t + i * 512;
            const unsigned p0 = (f2bf_u(xr[i].y) << 16) | f2bf_u(xr[i].x);
            const unsigned p1 = (f2bf_u(xr[i].w) << 16) | f2bf_u(xr[i].z);
            *(uint2*)&Ls[(s >> 5) * XRS + (s & 31) * 4] = make_uint2(p0, p1);
        }
        __syncthreads();   // bar1: stage visible; also guards prev epi reads

        // ---- prefetch next tile's x while computing this one ----
        const int ntile = tile + GRID1;
        float4 xr2[4];
        if (ntile < NT) {
#pragma unroll
            for (int i = 0; i < 4; ++i) {
                const int s  = t + i * 512;
                int gr = ntile * 64 + (s >> 5);
                if (gr >= N_NODES) gr = N_NODES - 1;
                xr2[i] = *(const float4*)(x + (size_t)gr * D + (s & 31) * 4);
            }
        } else {
#pragma unroll
            for (int i = 0; i < 4; ++i) xr2[i] = xr[i];
        }

        // ---- MFMA: A=Wf(W1^T), B=x -> D[m=j][n=node] ----
        f4 acc[4][2];
#pragma unroll
        for (int i = 0; i < 4; ++i)
#pragma unroll
            for (int j = 0; j < 2; ++j) acc[i][j] = (f4){0.f, 0.f, 0.f, 0.f};

#pragma unroll
        for (int ks = 0; ks < 4; ++ks) {
            const int kcol = ks * 32 + q * 8;
            short8 xf[4];
#pragma unroll
            for (int rt = 0; rt < 4; ++rt)
                xf[rt] = *(const short8*)&Ls[(rt * 16 + m16) * XRS + kcol];
#pragma unroll
            for (int rt = 0; rt < 4; ++rt)
#pragma unroll
                for (int ct = 0; ct < 2; ++ct)
                    acc[rt][ct] = __builtin_amdgcn_mfma_f32_16x16x32_bf16(
                        wfr[ks][ct], xf[rt], acc[rt][ct], 0, 0, 0);
        }

        // ---- epilogue: C-frags -> Es row-major (b64 per frag) ----
        // (no barrier needed before this: Es != stage region; prev-iter Es
        //  reads completed before this iter's bar1)
#pragma unroll
        for (int rt = 0; rt < 4; ++rt)
#pragma unroll
            for (int ct = 0; ct < 2; ++ct) {
                const int node = rt * 16 + m16;
                const int j    = h * 128 + cbase + ct * 16 + q * 4;
                const unsigned p0 =
                    (f2bf_u(acc[rt][ct][1] + badd[ct].y) << 16) |
                     f2bf_u(acc[rt][ct][0] + badd[ct].x);
                const unsigned p1 =
                    (f2bf_u(acc[rt][ct][3] + badd[ct].w) << 16) |
                     f2bf_u(acc[rt][ct][2] + badd[ct].z);
                *(uint2*)&Es[node * ERS + j] = make_uint2(p0, p1);
            }
        __syncthreads();   // bar2: epi visible (also: all stage reads done,
                           // so next iter may rewrite stage after loop)

        // ---- coalesced store: row t>>3, 32-col chunk (t&7)*32 (64 B) ----
        const int r    = t >> 3;
        const int c0   = (t & 7) * 32;
        const int grow = nb + r;
        if (grow < N_NODES) {
            const uint4* s = (const uint4*)&Es[r * ERS + c0];
            uint4* d = (uint4*)(UVb + (size_t)grow * 256 + c0);
#pragma unroll
            for (int i = 0; i < 4; ++i) d[i] = s[i];
        }

#pragma unroll
        for (int i = 0; i < 4; ++i) xr[i] = xr2[i];
    }
}

// ---------------------------------------------------------------------------
// Phase 2 (measured at gather roofline ~6.7 TB/s effective — unchanged):
// out[e] = relu(U[src]+V[tar]) . W2 + b2, UV in bf16.
// Block = 256 thr, 512 edges. Indices staged coalesced into LDS once.
// Each 16-lane group: 4 edges/iter, 8 independent 16-B gathers, 8 iters,
// unroll 2 -> up to 16 gathers in flight. float4 output stores.
// ---------------------------------------------------------------------------
__global__ __launch_bounds__(256) void edge_score_bf(
    const unsigned short* __restrict__ UVb,
    const int* __restrict__ pos,            // [2, E_POS]
    const int* __restrict__ neg,            // [2, E_NEG]
    const float* __restrict__ W2,           // [128]
    const float* __restrict__ b2,           // [1]
    float* __restrict__ out)                // [E_TOT]
{
    __shared__ int sidx[512], tidx[512];

    const int t   = threadIdx.x;
    const int bid = blockIdx.x;
    const int e0  = bid * 512;                       // global edge base
    const int* eidx = (bid < 512) ? pos : neg;       // E_POS = 512*512
    const int lb    = (bid < 512) ? e0 : e0 - E_POS;

    {
        const int2 sp = *(const int2*)(eidx + lb + 2 * t);
        const int2 tp = *(const int2*)(eidx + E_POS + lb + 2 * t);
        *(int2*)&sidx[2 * t] = sp;
        *(int2*)&tidx[2 * t] = tp;
    }
    __syncthreads();

    const int g   = t >> 4;
    const int l16 = t & 15;
    const float4 wa = *(const float4*)(W2 + l16 * 8);
    const float4 wb = *(const float4*)(W2 + l16 * 8 + 4);
    const float bb = b2[0];

#define BF_LO(uv) __uint_as_float((uv) << 16)
#define BF_HI(uv) __uint_as_float((uv) & 0xffff0000u)
#define ACC8(P, U, V)                                                   \
    P = fmaf(fmaxf(BF_LO(U.x) + BF_LO(V.x), 0.f), wa.x, P);             \
    P = fmaf(fmaxf(BF_HI(U.x) + BF_HI(V.x), 0.f), wa.y, P);             \
    P = fmaf(fmaxf(BF_LO(U.y) + BF_LO(V.y), 0.f), wa.z, P);             \
    P = fmaf(fmaxf(BF_HI(U.y) + BF_HI(V.y), 0.f), wa.w, P);             \
    P = fmaf(fmaxf(BF_LO(U.z) + BF_LO(V.z), 0.f), wb.x, P);             \
    P = fmaf(fmaxf(BF_HI(U.z) + BF_HI(V.z), 0.f), wb.y, P);             \
    P = fmaf(fmaxf(BF_LO(U.w) + BF_LO(V.w), 0.f), wb.z, P);             \
    P = fmaf(fmaxf(BF_HI(U.w) + BF_HI(V.w), 0.f), wb.w, P);

#pragma unroll 2
    for (int k = 0; k < 8; ++k) {
        const int el = k * 64 + g * 4;      // 4 consecutive local edges
        const int4 ss = *(const int4*)&sidx[el];
        const int4 tt = *(const int4*)&tidx[el];
        const uint4 U0 = *(const uint4*)(UVb + (size_t)ss.x * 256 + l16 * 8);
        const uint4 U1 = *(const uint4*)(UVb + (size_t)ss.y * 256 + l16 * 8);
        const uint4 U2 = *(const uint4*)(UVb + (size_t)ss.z * 256 + l16 * 8);
        const uint4 U3 = *(const uint4*)(UVb + (size_t)ss.w * 256 + l16 * 8);
        const uint4 V0 = *(const uint4*)(UVb + (size_t)tt.x * 256 + 128 + l16 * 8);
        const uint4 V1 = *(const uint4*)(UVb + (size_t)tt.y * 256 + 128 + l16 * 8);
        const uint4 V2 = *(const uint4*)(UVb + (size_t)tt.z * 256 + 128 + l16 * 8);
        const uint4 V3 = *(const uint4*)(UVb + (size_t)tt.w * 256 + 128 + l16 * 8);

        float p0 = 0.f, p1 = 0.f, p2 = 0.f, p3 = 0.f;
        ACC8(p0, U0, V0)
        ACC8(p1, U1, V1)
        ACC8(p2, U2, V2)
        ACC8(p3, U3, V3)

#pragma unroll
        for (int off = 8; off; off >>= 1) {
            p0 += __shfl_xor(p0, off, 64);
            p1 += __shfl_xor(p1, off, 64);
            p2 += __shfl_xor(p2, off, 64);
            p3 += __shfl_xor(p3, off, 64);
        }

        if (l16 == 0)
            *(float4*)(out + e0 + el) =
                make_float4(p0 + bb, p1 + bb, p2 + bb, p3 + bb);
    }
#undef ACC8
#undef BF_LO
#undef BF_HI
}

// ---------------------------------------------------------------------------
// Fallback (ws too small): one wave per edge, direct fp32 compute.
// ---------------------------------------------------------------------------
__global__ __launch_bounds__(64) void edge_naive(
    const float* __restrict__ x,
    const int* __restrict__ pos, const int* __restrict__ neg,
    const float* __restrict__ W1, const float* __restrict__ b1,
    const float* __restrict__ W2, const float* __restrict__ b2,
    float* __restrict__ out)
{
    const int lane = threadIdx.x;
    for (int e = blockIdx.x; e < E_TOT; e += gridDim.x) {
        int src, tar;
        if (e < E_POS) { src = pos[e]; tar = pos[E_POS + e]; }
        else { int e2 = e - E_POS; src = neg[e2]; tar = neg[E_NEG + e2]; }
        const float* xsrc = x + (size_t)src * D;
        const float* xtar = x + (size_t)tar * D;
        int j = lane * 2;
        float h0 = b1[j], h1 = b1[j + 1];
        for (int k = 0; k < D; ++k) {
            float a = xsrc[k], b = xtar[k];
            h0 = fmaf(a, W1[(size_t)k * D + j],       h0);
            h0 = fmaf(b, W1[(size_t)(k + D) * D + j], h0);
            h1 = fmaf(a, W1[(size_t)k * D + j + 1],       h1);
            h1 = fmaf(b, W1[(size_t)(k + D) * D + j + 1], h1);
        }
        float p = fmaf(fmaxf(h0, 0.f), W2[j], fmaxf(h1, 0.f) * W2[j + 1]);
#pragma unroll
        for (int off = 32; off > 0; off >>= 1) p += __shfl_xor(p, off, 64);
        if (lane == 0) out[e] = p + b2[0];
    }
}

extern "C" void kernel_launch(void* const* d_in, const int* in_sizes, int n_in,
                              void* d_out, int out_size, void* d_ws, size_t ws_size,
                              hipStream_t stream) {
    const float* x   = (const float*)d_in[0];
    const int*   pos = (const int*)d_in[1];
    const int*   neg = (const int*)d_in[2];
    const float* W1  = (const float*)d_in[3];
    const float* b1  = (const float*)d_in[4];
    const float* W2  = (const float*)d_in[5];
    const float* b2  = (const float*)d_in[6];
    float* out = (float*)d_out;

    const size_t uv_bytes = (size_t)N_NODES * 256 * sizeof(unsigned short);
    const size_t wf_bytes = 32768 * sizeof(unsigned short);
    if (ws_size >= uv_bytes + wf_bytes) {
        unsigned short* UVb = (unsigned short*)d_ws;
        unsigned short* Wfr = (unsigned short*)((char*)d_ws + uv_bytes);
        pack_w1<<<16, 256, 0, stream>>>(W1, Wfr);
        node_gemm_mfma<<<GRID1, 512, 0, stream>>>(x, Wfr, b1, UVb);
        edge_score_bf<<<E_TOT / 512, 256, 0, stream>>>(UVb, pos, neg, W2, b2, out);
    } else {
        edge_naive<<<8192, 64, 0, stream>>>(x, pos, neg, W1, b1, W2, b2, out);
    }
}